// Round 1
// baseline (8118.349 us; speedup 1.0000x reference)
//
#include <hip/hip_runtime.h>

#define BATCH 4
#define NCAP 4      // NC: input capsule groups
#define CIN 16      // input channels per group (LC)
#define NPAR 8      // NP
#define LPAR 16     // LP
#define OCH 128     // NP*LP
#define HH 256
#define WW 256
#define HWSZ (HH*WW)

// One thread per (pixel, nc). Block = 256 threads = 64 pixels (8x8 tile) x 4 nc.
// Lane layout: tid = pixel*4 + nc  -> the 4 nc-partners of a pixel are adjacent
// lanes, so cross-NC reduction is a 2-step __shfl_xor butterfly (bitwise
// deterministic: fp add is commutative).
__global__ __launch_bounds__(256)
void capsule_fused_kernel(const float* __restrict__ x,
                          const float* __restrict__ Wt,
                          float* __restrict__ out) {
    const int tid = threadIdx.x;
    const int nc  = tid & 3;
    const int p   = tid >> 2;            // 0..63
    const int py  = p >> 3, px = p & 7;

    const int blk  = blockIdx.x;         // b*1024 + tile
    const int b    = blk >> 10;
    const int tile = blk & 1023;
    const int th   = tile >> 5, tw = tile & 31;   // 32x32 tiles of 8x8 pixels
    const int h0   = th * 8 + py;
    const int w0   = tw * 8 + px;

    // ---- conv: votes[oc] for this (pixel, nc) ----
    float votes[OCH];
#pragma unroll
    for (int i = 0; i < OCH; ++i) votes[i] = 0.f;

    const float* xb = x + ((size_t)(b * NCAP + nc) * CIN) * HWSZ;

    for (int ci = 0; ci < CIN; ++ci) {
        // 5x5 input window, zero-padded
        float xw[25];
#pragma unroll
        for (int dy = 0; dy < 5; ++dy) {
            const int yy = h0 + dy - 2;
#pragma unroll
            for (int dx = 0; dx < 5; ++dx) {
                const int xx = w0 + dx - 2;
                const bool ok = (yy >= 0) && (yy < HH) && (xx >= 0) && (xx < WW);
                xw[dy * 5 + dx] = ok ? xb[(size_t)ci * HWSZ + yy * WW + xx] : 0.f;
            }
        }
        const float* wci = Wt + ci * 25;
#pragma unroll
        for (int oc = 0; oc < OCH; ++oc) {
            const float* wrow = wci + (size_t)oc * (CIN * 25);
            float wv[25];                 // wave-uniform -> scalar loads
#pragma unroll
            for (int t = 0; t < 25; ++t) wv[t] = wrow[t];
            float acc = votes[oc];
#pragma unroll
            for (int t = 0; t < 25; ++t) acc = fmaf(xw[t], wv[t], acc);
            votes[oc] = acc;
        }
    }

    // ---- dynamic routing (3 iterations), per-pixel independent ----
    float sims[NPAR];
#pragma unroll
    for (int i = 0; i < NPAR; ++i) sims[i] = 0.f;

    float* outb = out + (size_t)b * OCH * HWSZ + (size_t)h0 * WW + w0;

    for (int it = 0; it < 3; ++it) {
        // softmax over NP (in-thread; +1e-4 shift is softmax-invariant)
        float mx = sims[0];
#pragma unroll
        for (int i = 1; i < NPAR; ++i) mx = fmaxf(mx, sims[i]);
        float e[NPAR];
        float se = 0.f;
#pragma unroll
        for (int i = 0; i < NPAR; ++i) { e[i] = __expf(sims[i] - mx); se += e[i]; }
        const float inv = 1.f / se;

#pragma unroll
        for (int np_ = 0; np_ < NPAR; ++np_) {
            const float c = e[np_] * inv;
            float pb[LPAR];               // parent_bs for this np (all nc-lanes get full sum)
#pragma unroll
            for (int lp = 0; lp < LPAR; ++lp) {
                float v = c * votes[np_ * LPAR + lp];
                v += __shfl_xor(v, 1);
                v += __shfl_xor(v, 2);
                pb[lp] = v;
            }
            float n2 = 0.f, dot = 0.f;
#pragma unroll
            for (int lp = 0; lp < LPAR; ++lp) {
                n2  = fmaf(pb[lp], pb[lp], n2);
                dot = fmaf(votes[np_ * LPAR + lp], pb[lp], dot);
            }
            const float scale = sqrtf(n2) / (1.f + n2 + 1e-4f);  // squash factor
            sims[np_] += scale * dot;     // sum_lp votes * (scale*pb)

            if (it == 2) {
                // write parent: this lane writes lp in [nc*4, nc*4+4)
#pragma unroll
                for (int j = 0; j < 4; ++j) {
                    const int lp = nc * 4 + j;
                    outb[(size_t)(np_ * LPAR + lp) * HWSZ] = scale * pb[lp];
                }
            }
        }
    }
}

extern "C" void kernel_launch(void* const* d_in, const int* in_sizes, int n_in,
                              void* d_out, int out_size, void* d_ws, size_t ws_size,
                              hipStream_t stream) {
    const float* x  = (const float*)d_in[0];   // (4,4,16,256,256) f32
    const float* Wt = (const float*)d_in[1];   // (128,16,5,5) f32
    float* out = (float*)d_out;                // (4,8,16,256,256) f32
    (void)in_sizes; (void)n_in; (void)d_ws; (void)ws_size; (void)out_size;

    dim3 grid(BATCH * 32 * 32);   // b * (32x32 tiles)
    dim3 block(256);
    hipLaunchKernelGGL(capsule_fused_kernel, grid, block, 0, stream, x, Wt, out);
}

// Round 2
// 958.109 us; speedup vs baseline: 8.4733x; 8.4733x over previous
//
#include <hip/hip_runtime.h>

#define NPAR 8
#define LPAR 16
#define OCH 128
#define HH 256
#define WW 256
#define HWSZ (HH*WW)

typedef _Float16 f16x8 __attribute__((ext_vector_type(8)));
typedef float    f32x4 __attribute__((ext_vector_type(4)));

// LDS (halves), unioned:
//   conv phase : xs = [5][68][4 nc][16 ci]  at 0      (21760 halves, 43520 B)
//                wl = [128 oc][32 k]        at 21760  ( 4096 halves,  8192 B)
//   routing    : votes = [256 rows][136]    at 0      (34816 halves, 69632 B)
#define WL_OFF 21760
#define SMEM_HALVES 34816
#define VROW 136   // 128 oc + 8 pad halves

__global__ __launch_bounds__(256, 2)
void capsule_mfma_kernel(const float* __restrict__ x,
                         const float* __restrict__ Wg,
                         float* __restrict__ out) {
    __shared__ _Float16 sm[SMEM_HALVES];

    const int tid = threadIdx.x;
    const int w   = tid >> 6;          // wave 0..3
    const int l   = tid & 63;

    const int blk  = blockIdx.x;
    const int b    = blk >> 10;
    const int hrow = (blk & 1023) >> 2;
    const int w0   = (blk & 3) * 64;   // 64-wide row tile

    // ---- stage x tile: rows r = (nc*16+ci)*5+dy, 68 w each, fp16 ----
    for (int i = 0; i < 80; ++i) {
        const int r  = i * 4 + w;              // 0..319
        const int nc = r / 80;
        const int ci = (r / 5) & 15;
        const int dy = r % 5;
        const int hh = hrow + dy - 2;
        const bool hok = (hh >= 0) && (hh < HH);
        const float* src = x + (((size_t)(b * 4 + nc) * 16 + ci) * HH + hh) * (size_t)WW;
        {
            const int wp = l;
            const int wg = w0 + wp - 2;
            const float val = (hok && wg >= 0 && wg < WW) ? src[wg] : 0.f;
            int ah = (dy * 68 + wp) * 64 + nc * 16 + ci;
            ah ^= (wp & 1) << 3;               // bank swizzle (ci bit3)
            sm[ah] = (_Float16)val;
        }
        if (l < 4) {
            const int wp = l + 64;
            const int wg = w0 + wp - 2;
            const float val = (hok && wg >= 0 && wg < WW) ? src[wg] : 0.f;
            int ah = (dy * 68 + wp) * 64 + nc * 16 + ci;
            ah ^= (wp & 1) << 3;
            sm[ah] = (_Float16)val;
        }
    }

    // ---- MFMA conv: M=256 (px*4+nc), N=128 (oc), K=416 (tap*16+ci) ----
    const int p   = l >> 4;            // k-group
    const int ml  = l & 15;
    const int ciA = (p & 1) * 8;       // ci0 of A frag
    const int pxA = ml >> 2;           // px offset within M-subtile
    const int ncA = ml & 3;

    f32x4 acc[4][8];
#pragma unroll
    for (int a = 0; a < 4; ++a)
#pragma unroll
        for (int bb = 0; bb < 8; ++bb)
            acc[a][bb] = (f32x4){0.f, 0.f, 0.f, 0.f};

    for (int kk = 0; kk < 13; ++kk) {
        // stage W chunk (taps 2kk, 2kk+1): wl[oc][tl*16+ci]
#pragma unroll
        for (int i = 0; i < 16; ++i) {
            const int e  = i * 256 + tid;
            const int ci = e & 15;
            const int tl = (e >> 4) & 1;
            const int oc = e >> 5;
            const int tg = 2 * kk + tl;
            const float v = (tg < 25) ? Wg[oc * 400 + ci * 25 + tg] : 0.f;
            sm[WL_OFF + e] = (_Float16)v;
        }
        __syncthreads();

        int tap = 2 * kk + (p >> 1);
        if (tap > 24) tap = 24;        // pad taps: B side is zero
        const int dy = tap / 5;
        const int dx = tap - 5 * dy;

        f16x8 af[4];
#pragma unroll
        for (int a = 0; a < 4; ++a) {
            const int px = (4 * w + a) * 4 + pxA;
            const int wp = px + dx;
            int ah = (dy * 68 + wp) * 64 + ncA * 16 + ciA;
            ah ^= (wp & 1) << 3;
            af[a] = *(const f16x8*)&sm[ah];
        }
        f16x8 bf[8];
#pragma unroll
        for (int bb = 0; bb < 8; ++bb) {
            const int oc = bb * 16 + ml;
            bf[bb] = *(const f16x8*)&sm[WL_OFF + oc * 32 + p * 8];
        }
#pragma unroll
        for (int a = 0; a < 4; ++a)
#pragma unroll
            for (int bb = 0; bb < 8; ++bb)
                acc[a][bb] = __builtin_amdgcn_mfma_f32_16x16x32_f16(
                    af[a], bf[bb], acc[a][bb], 0, 0, 0);
        __syncthreads();
    }

    // ---- epilogue: acc -> votes LDS (fp16). C layout: row=(l>>4)*4+reg, col=l&15
#pragma unroll
    for (int a = 0; a < 4; ++a) {
        const int px = (4 * w + a) * 4 + p;
#pragma unroll
        for (int bb = 0; bb < 8; ++bb) {
            const int oc = bb * 16 + ml;
#pragma unroll
            for (int reg = 0; reg < 4; ++reg) {
                sm[(px * 4 + reg) * VROW + oc] = (_Float16)acc[a][bb][reg];
            }
        }
    }
    __syncthreads();

    // ---- routing: thread = px*4+nc (round-1 verified structure) ----
    float v[OCH];
#pragma unroll
    for (int c = 0; c < 16; ++c) {
        const f16x8 h = *(const f16x8*)&sm[tid * VROW + c * 8];
#pragma unroll
        for (int j = 0; j < 8; ++j) v[c * 8 + j] = (float)h[j];
    }

    const int ncR = tid & 3;
    const int pxR = tid >> 2;
    float* outb = out + (size_t)b * OCH * HWSZ + (size_t)hrow * WW + (w0 + pxR);

    float sims[NPAR];
#pragma unroll
    for (int i = 0; i < NPAR; ++i) sims[i] = 0.f;

    for (int it = 0; it < 3; ++it) {
        float mx = sims[0];
#pragma unroll
        for (int i = 1; i < NPAR; ++i) mx = fmaxf(mx, sims[i]);
        float e[NPAR];
        float se = 0.f;
#pragma unroll
        for (int i = 0; i < NPAR; ++i) { e[i] = __expf(sims[i] - mx); se += e[i]; }
        const float inv = 1.f / se;

#pragma unroll
        for (int np_ = 0; np_ < NPAR; ++np_) {
            const float c = e[np_] * inv;
            float pb[LPAR];
#pragma unroll
            for (int lp = 0; lp < LPAR; ++lp) {
                float t = c * v[np_ * LPAR + lp];
                t += __shfl_xor(t, 1);
                t += __shfl_xor(t, 2);
                pb[lp] = t;
            }
            float n2 = 0.f, dot = 0.f;
#pragma unroll
            for (int lp = 0; lp < LPAR; ++lp) {
                n2  = fmaf(pb[lp], pb[lp], n2);
                dot = fmaf(v[np_ * LPAR + lp], pb[lp], dot);
            }
            const float scale = sqrtf(n2) / (1.f + n2 + 1e-4f);
            sims[np_] += scale * dot;

            if (it == 2) {
#pragma unroll
                for (int j = 0; j < 4; ++j) {
                    const int lp = ncR * 4 + j;
                    outb[(size_t)(np_ * LPAR + lp) * HWSZ] = scale * pb[lp];
                }
            }
        }
    }
}

extern "C" void kernel_launch(void* const* d_in, const int* in_sizes, int n_in,
                              void* d_out, int out_size, void* d_ws, size_t ws_size,
                              hipStream_t stream) {
    const float* x  = (const float*)d_in[0];   // (4,4,16,256,256) f32
    const float* Wg = (const float*)d_in[1];   // (128,16,5,5) f32
    float* out = (float*)d_out;                // (4,8,16,256,256) f32
    (void)in_sizes; (void)n_in; (void)d_ws; (void)ws_size; (void)out_size;

    dim3 grid(4096);   // 4 b * 256 h * 4 wtiles
    dim3 block(256);
    hipLaunchKernelGGL(capsule_mfma_kernel, grid, block, 0, stream, x, Wg, out);
}

// Round 3
// 732.564 us; speedup vs baseline: 11.0821x; 1.3079x over previous
//
#include <hip/hip_runtime.h>

#define NPAR 8
#define LPAR 16
#define OCH 128
#define HH 256
#define WW 256
#define HWSZ (HH*WW)

typedef _Float16 f16x8 __attribute__((ext_vector_type(8)));
typedef _Float16 f16x2 __attribute__((ext_vector_type(2)));
typedef float    f32x4 __attribute__((ext_vector_type(4)));

// LDS (halves), unioned:
//   conv phase : xs = [5 dy][68 wp][64 col], col = nc*16+ci, XOR-swizzled
//                (21760 halves = 43520 B)
//   epilogue   : votes = [256 rows][136]  (34816 halves = 69632 B)
#define SMEM_HALVES 34816
#define VROW 136

// 16B-granule XOR swizzle: spreads the 128B-stride wp rows over 8 bank-groups.
__device__ __forceinline__ int xs_addr(int dy, int wp, int col) {
    return (dy * 68 + wp) * 64 + (col ^ ((wp & 7) << 3));
}

// Pre-pass: reorder W (f32 [128 oc][16 ci][25 tap]) -> ws fp16 [13 kk][128 oc][32 q]
// q = p*8+j with tap = 2kk+(p>>1), ci = (p&1)*8 + j  (exact B-fragment order).
__global__ void reorder_W_kernel(const float* __restrict__ Wg,
                                 _Float16* __restrict__ ws) {
    int idx = blockIdx.x * 256 + threadIdx.x;
    if (idx >= 13 * 128 * 32) return;
    const int q  = idx & 31;
    const int oc = (idx >> 5) & 127;
    const int kk = idx >> 12;
    const int tap = 2 * kk + (q >> 4);
    const int ci  = ((q >> 3) & 1) * 8 + (q & 7);
    const float v = (tap < 25) ? Wg[oc * 400 + ci * 25 + tap] : 0.f;
    ws[idx] = (_Float16)v;
}

__global__ __launch_bounds__(256, 2)
void capsule_mfma2_kernel(const float* __restrict__ x,
                          const _Float16* __restrict__ wsf,
                          float* __restrict__ out) {
    __shared__ _Float16 sm[SMEM_HALVES];

    const int tid = threadIdx.x;
    const int w   = tid >> 6;          // wave 0..3
    const int l   = tid & 63;

    const int blk  = blockIdx.x;
    const int b    = blk >> 10;
    const int hrow = (blk & 1023) >> 2;
    const int w0   = (blk & 3) * 64;   // 64-wide row tile

    // ---- stage x tile: 160 rows (nc,ci-pair,dy), 68 wp each, paired-ci b32 writes
    for (int i = 0; i < 40; ++i) {
        const int r   = i * 4 + w;             // 0..159
        const int nc  = r / 40;
        const int rem = r - nc * 40;
        const int cip = rem / 5;
        const int dy  = rem - cip * 5;
        const int ci0 = cip * 2;
        const int hh  = hrow + dy - 2;
        const bool hok = (hh >= 0) && (hh < HH);
        const float* src = x + (((size_t)(b * 4 + nc) * 16 + ci0) * HH + hh) * (size_t)WW;
        const int col = nc * 16 + ci0;
        {
            const int wp = l, wg = w0 + wp - 2;
            const bool ok = hok && (wg >= 0) && (wg < WW);
            const float v0 = ok ? src[wg] : 0.f;
            const float v1 = ok ? src[HWSZ + wg] : 0.f;
            *(f16x2*)&sm[xs_addr(dy, wp, col)] = (f16x2){(_Float16)v0, (_Float16)v1};
        }
        if (l < 4) {
            const int wp = l + 64, wg = w0 + wp - 2;
            const bool ok = hok && (wg >= 0) && (wg < WW);
            const float v0 = ok ? src[wg] : 0.f;
            const float v1 = ok ? src[HWSZ + wg] : 0.f;
            *(f16x2*)&sm[xs_addr(dy, wp, col)] = (f16x2){(_Float16)v0, (_Float16)v1};
        }
    }
    __syncthreads();

    // ---- MFMA conv: M=256 (px*4+nc), N=128 (oc), K=416; barrier-free loop ----
    const int p   = l >> 4;
    const int ml  = l & 15;
    const int ciA = (p & 1) * 8;
    const int pxA = ml >> 2;
    const int ncA = ml & 3;

    f32x4 acc[4][8];
#pragma unroll
    for (int a = 0; a < 4; ++a)
#pragma unroll
        for (int bb = 0; bb < 8; ++bb)
            acc[a][bb] = (f32x4){0.f, 0.f, 0.f, 0.f};

#pragma unroll
    for (int kk = 0; kk < 13; ++kk) {
        // B frags straight from global (L2-hot, 1KB contiguous per instruction)
        f16x8 bf[8];
#pragma unroll
        for (int bb = 0; bb < 8; ++bb)
            bf[bb] = *(const f16x8*)&wsf[(kk * 128 + bb * 16 + ml) * 32 + p * 8];

        int tap = 2 * kk + (p >> 1);
        if (tap > 24) tap = 24;        // pad taps: B side is zero
        const int dy = tap / 5;
        const int dx = tap - 5 * dy;

        f16x8 af[4];
#pragma unroll
        for (int a = 0; a < 4; ++a) {
            const int wp = (4 * w + a) * 4 + pxA + dx;
            af[a] = *(const f16x8*)&sm[xs_addr(dy, wp, ncA * 16 + ciA)];
        }
#pragma unroll
        for (int a = 0; a < 4; ++a)
#pragma unroll
            for (int bb = 0; bb < 8; ++bb)
                acc[a][bb] = __builtin_amdgcn_mfma_f32_16x16x32_f16(
                    af[a], bf[bb], acc[a][bb], 0, 0, 0);
    }
    __syncthreads();   // xs region about to be overwritten by votes

    // ---- epilogue: acc -> votes LDS (fp16). C layout: row=(l>>4)*4+reg, col=l&15
#pragma unroll
    for (int a = 0; a < 4; ++a) {
        const int px = (4 * w + a) * 4 + p;
#pragma unroll
        for (int bb = 0; bb < 8; ++bb) {
            const int oc = bb * 16 + ml;
#pragma unroll
            for (int reg = 0; reg < 4; ++reg) {
                sm[(px * 4 + reg) * VROW + oc] = (_Float16)acc[a][bb][reg];
            }
        }
    }
    __syncthreads();

    // ---- routing: thread = px*4+nc (verified structure) ----
    float v[OCH];
#pragma unroll
    for (int c = 0; c < 16; ++c) {
        const f16x8 h = *(const f16x8*)&sm[tid * VROW + c * 8];
#pragma unroll
        for (int j = 0; j < 8; ++j) v[c * 8 + j] = (float)h[j];
    }

    const int ncR = tid & 3;
    const int pxR = tid >> 2;
    float* outb = out + (size_t)b * OCH * HWSZ + (size_t)hrow * WW + (w0 + pxR);

    float sims[NPAR];
#pragma unroll
    for (int i = 0; i < NPAR; ++i) sims[i] = 0.f;

    for (int it = 0; it < 3; ++it) {
        float mx = sims[0];
#pragma unroll
        for (int i = 1; i < NPAR; ++i) mx = fmaxf(mx, sims[i]);
        float e[NPAR];
        float se = 0.f;
#pragma unroll
        for (int i = 0; i < NPAR; ++i) { e[i] = __expf(sims[i] - mx); se += e[i]; }
        const float inv = 1.f / se;

#pragma unroll
        for (int np_ = 0; np_ < NPAR; ++np_) {
            const float c = e[np_] * inv;
            float pb[LPAR];
#pragma unroll
            for (int lp = 0; lp < LPAR; ++lp) {
                float t = c * v[np_ * LPAR + lp];
                t += __shfl_xor(t, 1);
                t += __shfl_xor(t, 2);
                pb[lp] = t;
            }
            float n2 = 0.f, dot = 0.f;
#pragma unroll
            for (int lp = 0; lp < LPAR; ++lp) {
                n2  = fmaf(pb[lp], pb[lp], n2);
                dot = fmaf(v[np_ * LPAR + lp], pb[lp], dot);
            }
            const float scale = sqrtf(n2) / (1.f + n2 + 1e-4f);
            sims[np_] += scale * dot;

            if (it == 2) {
#pragma unroll
                for (int j = 0; j < 4; ++j) {
                    const int lp = ncR * 4 + j;
                    outb[(size_t)(np_ * LPAR + lp) * HWSZ] = scale * pb[lp];
                }
            }
        }
    }
}

extern "C" void kernel_launch(void* const* d_in, const int* in_sizes, int n_in,
                              void* d_out, int out_size, void* d_ws, size_t ws_size,
                              hipStream_t stream) {
    const float* x  = (const float*)d_in[0];   // (4,4,16,256,256) f32
    const float* Wg = (const float*)d_in[1];   // (128,16,5,5) f32
    float* out = (float*)d_out;                // (4,8,16,256,256) f32
    _Float16* ws = (_Float16*)d_ws;            // 13*128*32 halves = 106496 B
    (void)in_sizes; (void)n_in; (void)ws_size; (void)out_size;

    hipLaunchKernelGGL(reorder_W_kernel, dim3(208), dim3(256), 0, stream, Wg, ws);
    hipLaunchKernelGGL(capsule_mfma2_kernel, dim3(4096), dim3(256), 0, stream,
                       x, ws, out);
}

// Round 4
// 529.175 us; speedup vs baseline: 15.3415x; 1.3843x over previous
//
#include <hip/hip_runtime.h>

#define NPAR 8
#define LPAR 16
#define OCH 128
#define HH 256
#define WW 256
#define HWSZ (HH*WW)

typedef _Float16 f16x8 __attribute__((ext_vector_type(8)));
typedef _Float16 f16x2 __attribute__((ext_vector_type(2)));
typedef float    f32x4 __attribute__((ext_vector_type(4)));

// LDS (halves), unioned:
//   conv phase : xs = [8 dyr][20 wp][64 col], col = nc*16+ci, XOR-swizzled
//                (10240 halves = 20480 B)
//   epilogue   : votes = [256 rows][136], col = lp*8+np  (34816 halves = 69632 B)
#define SMEM_HALVES 34816
#define VROW 136

__device__ __forceinline__ int xs_addr(int dyr, int wp, int col) {
    return (dyr * 20 + wp) * 64 + (col ^ ((wp & 7) << 3));
}

// sum over each aligned quad of lanes via DPP quad_perm (pure VALU, no DS pipe)
__device__ __forceinline__ float quad_sum4(float v) {
    int t = __builtin_amdgcn_update_dpp(0, __float_as_int(v), 0xB1, 0xF, 0xF, true); // [1,0,3,2]
    v += __int_as_float(t);
    t = __builtin_amdgcn_update_dpp(0, __float_as_int(v), 0x4E, 0xF, 0xF, true);     // [2,3,0,1]
    v += __int_as_float(t);
    return v;
}

// Pre-pass: W (f32 [128 oc][16 ci][25 tap]) -> ws fp16 [13 kk][128 oc][32 q]
// q = p*8+j with tap = 2kk+(p>>1), ci = (p&1)*8 + j  (exact B-fragment order).
__global__ void reorder_W_kernel(const float* __restrict__ Wg,
                                 _Float16* __restrict__ ws) {
    int idx = blockIdx.x * 256 + threadIdx.x;
    if (idx >= 13 * 128 * 32) return;
    const int q  = idx & 31;
    const int oc = (idx >> 5) & 127;
    const int kk = idx >> 12;
    const int tap = 2 * kk + (q >> 4);
    const int ci  = ((q >> 3) & 1) * 8 + (q & 7);
    const float v = (tap < 25) ? Wg[oc * 400 + ci * 25 + tap] : 0.f;
    ws[idx] = (_Float16)v;
}

__global__ __launch_bounds__(256, 2)
void capsule_mfma3_kernel(const float* __restrict__ x,
                          const _Float16* __restrict__ wsf,
                          float* __restrict__ out) {
    __shared__ _Float16 sm[SMEM_HALVES];

    const int tid = threadIdx.x;
    const int w   = tid >> 6;          // wave 0..3 (== pixel row pxy)
    const int l   = tid & 63;

    const int blk   = blockIdx.x;
    const int b     = blk >> 10;
    const int rt    = blk & 1023;
    const int hrow0 = (rt >> 4) << 2;  // 64 row-tiles of 4 rows
    const int w0    = (rt & 15) << 4;  // 16 col-tiles of 16 px

    // ---- stage x tile [8 rows][20 cols][64 ch] as fp16, b32 ci-pair writes ----
    for (int i = 0; i < 20; ++i) {
        const unsigned idx = i * 256 + tid;          // 0..5119
        const unsigned q   = idx / 20u;              // magic-mul (const divisor)
        const int wp  = idx - q * 20u;
        const int cip = q & 7;
        const int t2  = q >> 3;
        const int nc  = t2 & 3;
        const int dyr = t2 >> 2;
        const int hh  = hrow0 + dyr - 2;
        const int wg  = w0 + wp - 2;
        const bool ok = (hh >= 0) && (hh < HH) && (wg >= 0) && (wg < WW);
        const float* src = x + (((size_t)(b * 4 + nc) * 16 + cip * 2) * HH + hh) * (size_t)WW + wg;
        const float v0 = ok ? src[0] : 0.f;
        const float v1 = ok ? src[HWSZ] : 0.f;
        *(f16x2*)&sm[xs_addr(dyr, wp, nc * 16 + cip * 2)] =
            (f16x2){(_Float16)v0, (_Float16)v1};
    }
    __syncthreads();

    // ---- MFMA conv: M=256 (px*4+nc), N=128 (oc), K=416; barrier-free loop ----
    const int p   = l >> 4;
    const int ml  = l & 15;
    const int ciA = (p & 1) * 8;
    const int pxA = ml >> 2;
    const int ncA = ml & 3;
    const int bfbase = ml * 32 + p * 8;

    f32x4 acc[4][8];
#pragma unroll
    for (int a = 0; a < 4; ++a)
#pragma unroll
        for (int bb = 0; bb < 8; ++bb)
            acc[a][bb] = (f32x4){0.f, 0.f, 0.f, 0.f};

#pragma unroll
    for (int kk = 0; kk < 13; ++kk) {
        f16x8 bf[8];
#pragma unroll
        for (int bb = 0; bb < 8; ++bb)
            bf[bb] = *(const f16x8*)&wsf[kk * 4096 + bb * 512 + bfbase];

        int tap = 2 * kk + (p >> 1);
        if (tap > 24) tap = 24;        // pad taps: B side is zero
        const int dy = tap / 5;
        const int dx = tap - 5 * dy;

        f16x8 af[4];
#pragma unroll
        for (int a = 0; a < 4; ++a)
            af[a] = *(const f16x8*)&sm[xs_addr(w + dy, a * 4 + pxA + dx, ncA * 16 + ciA)];

#pragma unroll
        for (int a = 0; a < 4; ++a)
#pragma unroll
            for (int bb = 0; bb < 8; ++bb)
                acc[a][bb] = __builtin_amdgcn_mfma_f32_16x16x32_f16(
                    af[a], bf[bb], acc[a][bb], 0, 0, 0);
    }
    __syncthreads();   // xs region about to be overwritten by votes

    // ---- epilogue: acc -> votes LDS fp16, packed b128 (col = lp*8 + np) ----
    // C layout: M-row = px*4 + nc with px = w*16 + a*4 + p, nc = reg; oc = bb*16+ml
#pragma unroll
    for (int a = 0; a < 4; ++a) {
        const int px = w * 16 + a * 4 + p;
#pragma unroll
        for (int reg = 0; reg < 4; ++reg) {
            f16x8 pk;
#pragma unroll
            for (int bb = 0; bb < 8; ++bb) pk[bb] = (_Float16)acc[a][bb][reg];
            *(f16x8*)&sm[(px * 4 + reg) * VROW + ml * 8] = pk;
        }
    }
    __syncthreads();

    // ---- routing: thread = px*4+nc; votes kept PACKED fp16 in regs (no spill) ----
    f16x8 vh[16];
#pragma unroll
    for (int c = 0; c < 16; ++c)
        vh[c] = *(const f16x8*)&sm[tid * VROW + c * 8];
    // v(np, lp) = vh[lp][np]

    const int ncR = tid & 3;
    const int pxx = (tid >> 2) & 15;
    float* outb = out + (size_t)b * OCH * HWSZ
                + (size_t)(hrow0 + w) * WW + (w0 + pxx);

    float sims[NPAR];
#pragma unroll
    for (int i = 0; i < NPAR; ++i) sims[i] = 0.f;

    for (int it = 0; it < 3; ++it) {
        float mx = sims[0];
#pragma unroll
        for (int i = 1; i < NPAR; ++i) mx = fmaxf(mx, sims[i]);
        float e[NPAR];
        float se = 0.f;
#pragma unroll
        for (int i = 0; i < NPAR; ++i) { e[i] = __expf(sims[i] - mx); se += e[i]; }
        const float inv = 1.f / se;

#pragma unroll
        for (int np_ = 0; np_ < NPAR; ++np_) {
            const float c = e[np_] * inv;
            float pb[LPAR];
#pragma unroll
            for (int lp = 0; lp < LPAR; ++lp)
                pb[lp] = quad_sum4(c * (float)vh[lp][np_]);   // nc-sum via DPP

            float n2 = 0.f, dot = 0.f;
#pragma unroll
            for (int lp = 0; lp < LPAR; ++lp) {
                n2  = fmaf(pb[lp], pb[lp], n2);
                dot = fmaf((float)vh[lp][np_], pb[lp], dot);
            }
            const float scale = sqrtf(n2) / (1.f + n2 + 1e-4f);
            sims[np_] += scale * dot;

            if (it == 2) {
                // lane stores lp = ncR*4+j; select pb via cndmask (static indices)
#pragma unroll
                for (int j = 0; j < 4; ++j) {
                    const float lo  = (ncR & 1) ? pb[4 + j]  : pb[j];
                    const float hi  = (ncR & 1) ? pb[12 + j] : pb[8 + j];
                    const float sel = (ncR & 2) ? hi : lo;
                    outb[(size_t)(np_ * LPAR + ncR * 4 + j) * HWSZ] = scale * sel;
                }
            }
        }
    }
}

extern "C" void kernel_launch(void* const* d_in, const int* in_sizes, int n_in,
                              void* d_out, int out_size, void* d_ws, size_t ws_size,
                              hipStream_t stream) {
    const float* x  = (const float*)d_in[0];   // (4,4,16,256,256) f32
    const float* Wg = (const float*)d_in[1];   // (128,16,5,5) f32
    float* out = (float*)d_out;                // (4,8,16,256,256) f32
    _Float16* ws = (_Float16*)d_ws;            // 13*128*32 halves = 106496 B
    (void)in_sizes; (void)n_in; (void)ws_size; (void)out_size;

    hipLaunchKernelGGL(reorder_W_kernel, dim3(208), dim3(256), 0, stream, Wg, ws);
    hipLaunchKernelGGL(capsule_mfma3_kernel, dim3(4096), dim3(256), 0, stream,
                       x, ws, out);
}

// Round 5
// 241.425 us; speedup vs baseline: 33.6268x; 2.1919x over previous
//
#include <hip/hip_runtime.h>

#define NPAR 8
#define LPAR 16
#define OCH 128
#define HH 256
#define WW 256
#define HWSZ (HH*WW)

typedef _Float16 f16x8 __attribute__((ext_vector_type(8)));
typedef _Float16 f16x2 __attribute__((ext_vector_type(2)));
typedef float    f32x4 __attribute__((ext_vector_type(4)));

// LDS (halves), unioned:
//   conv phase : xs = [8 dyr][20 wp][64 col], col = nc*16+ci, XOR-swizzled
//                (10240 halves = 20480 B)
//   epilogue   : votes = [256 rows][136], col = lp*8+np  (34816 halves = 69632 B)
#define SMEM_HALVES 34816
#define VROW 136

__device__ __forceinline__ int xs_addr(int dyr, int wp, int col) {
    return (dyr * 20 + wp) * 64 + (col ^ ((wp & 7) << 3));
}

// sum over each aligned quad of lanes via DPP quad_perm (pure VALU, no DS pipe)
__device__ __forceinline__ float quad_sum4(float v) {
    int t = __builtin_amdgcn_update_dpp(0, __float_as_int(v), 0xB1, 0xF, 0xF, true); // [1,0,3,2]
    v += __int_as_float(t);
    t = __builtin_amdgcn_update_dpp(0, __float_as_int(v), 0x4E, 0xF, 0xF, true);     // [2,3,0,1]
    v += __int_as_float(t);
    return v;
}

// Pre-pass: W (f32 [128 oc][16 ci][25 tap]) -> ws fp16 [13 kk][128 oc][32 q]
// q = p*8+j with tap = 2kk+(p>>1), ci = (p&1)*8 + j  (exact B-fragment order).
__global__ void reorder_W_kernel(const float* __restrict__ Wg,
                                 _Float16* __restrict__ ws) {
    int idx = blockIdx.x * 256 + threadIdx.x;
    if (idx >= 13 * 128 * 32) return;
    const int q  = idx & 31;
    const int oc = (idx >> 5) & 127;
    const int kk = idx >> 12;
    const int tap = 2 * kk + (q >> 4);
    const int ci  = ((q >> 3) & 1) * 8 + (q & 7);
    const float v = (tap < 25) ? Wg[oc * 400 + ci * 25 + tap] : 0.f;
    ws[idx] = (_Float16)v;
}

__global__ __launch_bounds__(256, 2)
void capsule_mfma4_kernel(const float* __restrict__ x,
                          const _Float16* __restrict__ wsf,
                          float* __restrict__ out) {
    __shared__ _Float16 sm[SMEM_HALVES];

    const int tid = threadIdx.x;
    const int w   = tid >> 6;          // wave 0..3 (== pixel row pxy)
    const int l   = tid & 63;

    // XCD-aware swizzle: 4096 wgs / 8 XCDs = 512 contiguous tiles per XCD.
    // Adjacent 16-px tiles (two halves of each 128B output line + shared x
    // halos) land in the same per-XCD L2.
    const int blk   = ((blockIdx.x & 7) << 9) + (blockIdx.x >> 3);
    const int b     = blk >> 10;
    const int rt    = blk & 1023;
    const int hrow0 = (rt >> 4) << 2;  // 64 row-tiles of 4 rows
    const int w0    = (rt & 15) << 4;  // 16 col-tiles of 16 px

    // ---- stage x tile [8 rows][20 cols][64 ch] as fp16, b32 ci-pair writes ----
    for (int i = 0; i < 20; ++i) {
        const unsigned idx = i * 256 + tid;          // 0..5119
        const unsigned q   = idx / 20u;              // magic-mul (const divisor)
        const int wp  = idx - q * 20u;
        const int cip = q & 7;
        const int t2  = q >> 3;
        const int nc  = t2 & 3;
        const int dyr = t2 >> 2;
        const int hh  = hrow0 + dyr - 2;
        const int wg  = w0 + wp - 2;
        const bool ok = (hh >= 0) && (hh < HH) && (wg >= 0) && (wg < WW);
        const float* src = x + (((size_t)(b * 4 + nc) * 16 + cip * 2) * HH + hh) * (size_t)WW + wg;
        const float v0 = ok ? src[0] : 0.f;
        const float v1 = ok ? src[HWSZ] : 0.f;
        *(f16x2*)&sm[xs_addr(dyr, wp, nc * 16 + cip * 2)] =
            (f16x2){(_Float16)v0, (_Float16)v1};
    }
    __syncthreads();

    // ---- MFMA conv: M=256 (px*4+nc), N=128 (oc), K=416; barrier-free loop ----
    const int p   = l >> 4;
    const int ml  = l & 15;
    const int ciA = (p & 1) * 8;
    const int pxA = ml >> 2;
    const int ncA = ml & 3;
    const int bfbase = ml * 32 + p * 8;

    f32x4 acc[4][8];
#pragma unroll
    for (int a = 0; a < 4; ++a)
#pragma unroll
        for (int bb = 0; bb < 8; ++bb)
            acc[a][bb] = (f32x4){0.f, 0.f, 0.f, 0.f};

#pragma unroll
    for (int kk = 0; kk < 13; ++kk) {
        f16x8 bf[8];
#pragma unroll
        for (int bb = 0; bb < 8; ++bb)
            bf[bb] = *(const f16x8*)&wsf[kk * 4096 + bb * 512 + bfbase];

        int tap = 2 * kk + (p >> 1);
        if (tap > 24) tap = 24;        // pad taps: B side is zero
        const int dy = tap / 5;
        const int dx = tap - 5 * dy;

        f16x8 af[4];
#pragma unroll
        for (int a = 0; a < 4; ++a)
            af[a] = *(const f16x8*)&sm[xs_addr(w + dy, a * 4 + pxA + dx, ncA * 16 + ciA)];

#pragma unroll
        for (int a = 0; a < 4; ++a)
#pragma unroll
            for (int bb = 0; bb < 8; ++bb)
                acc[a][bb] = __builtin_amdgcn_mfma_f32_16x16x32_f16(
                    af[a], bf[bb], acc[a][bb], 0, 0, 0);
    }
    __syncthreads();   // xs region about to be overwritten by votes

    // ---- epilogue: acc -> votes LDS fp16, packed b128 (col = lp*8 + np) ----
    // C layout: M-row = px*4 + nc with px = w*16 + a*4 + p, nc = reg; oc = bb*16+ml
#pragma unroll
    for (int a = 0; a < 4; ++a) {
        const int px = w * 16 + a * 4 + p;
#pragma unroll
        for (int reg = 0; reg < 4; ++reg) {
            f16x8 pk;
#pragma unroll
            for (int bb = 0; bb < 8; ++bb) pk[bb] = (_Float16)acc[a][bb][reg];
            *(f16x8*)&sm[(px * 4 + reg) * VROW + ml * 8] = pk;
        }
    }
    __syncthreads();

    // ---- routing: thread = px*4+nc; votes packed fp16 in regs; streaming pb
    //      (no pb[16] array -> live set ~99 arch VGPRs, no scratch spill) ----
    f16x8 vh[16];
#pragma unroll
    for (int c = 0; c < 16; ++c)
        vh[c] = *(const f16x8*)&sm[tid * VROW + c * 8];
    // v(np, lp) = vh[lp][np]

    const int ncR = tid & 3;
    const int pxx = (tid >> 2) & 15;
    float* outb = out + (size_t)b * OCH * HWSZ
                + (size_t)(hrow0 + w) * WW + (w0 + pxx);

    float sims[NPAR];
#pragma unroll
    for (int i = 0; i < NPAR; ++i) sims[i] = 0.f;

#pragma unroll
    for (int it = 0; it < 3; ++it) {
        float mx = sims[0];
#pragma unroll
        for (int i = 1; i < NPAR; ++i) mx = fmaxf(mx, sims[i]);
        float e[NPAR];
        float se = 0.f;
#pragma unroll
        for (int i = 0; i < NPAR; ++i) { e[i] = __expf(sims[i] - mx); se += e[i]; }
        const float inv = 1.f / se;

#pragma unroll
        for (int np_ = 0; np_ < NPAR; ++np_) {
            const float c = e[np_] * inv;
            float n2 = 0.f, dot = 0.f;
            float keep[4] = {0.f, 0.f, 0.f, 0.f};   // static-indexed only
#pragma unroll
            for (int lp = 0; lp < LPAR; ++lp) {
                const float vv = (float)vh[lp][np_];
                const float t  = quad_sum4(c * vv);      // pb[lp] via DPP nc-sum
                n2  = fmaf(t, t, n2);
                dot = fmaf(vv, t, dot);
                if (it == 2 && (lp >> 2) == ncR)         // cndmask, last it only
                    keep[lp & 3] = t;
            }
            const float scale = sqrtf(n2) / (1.f + n2 + 1e-4f);
            sims[np_] += scale * dot;

            if (it == 2) {
#pragma unroll
                for (int j = 0; j < 4; ++j)
                    outb[(size_t)(np_ * LPAR + ncR * 4 + j) * HWSZ] = scale * keep[j];
            }
        }
    }
}

extern "C" void kernel_launch(void* const* d_in, const int* in_sizes, int n_in,
                              void* d_out, int out_size, void* d_ws, size_t ws_size,
                              hipStream_t stream) {
    const float* x  = (const float*)d_in[0];   // (4,4,16,256,256) f32
    const float* Wg = (const float*)d_in[1];   // (128,16,5,5) f32
    float* out = (float*)d_out;                // (4,8,16,256,256) f32
    _Float16* ws = (_Float16*)d_ws;            // 13*128*32 halves = 106496 B
    (void)in_sizes; (void)n_in; (void)ws_size; (void)out_size;

    hipLaunchKernelGGL(reorder_W_kernel, dim3(208), dim3(256), 0, stream, Wg, ws);
    hipLaunchKernelGGL(capsule_mfma4_kernel, dim3(4096), dim3(256), 0, stream,
                       x, ws, out);
}